// Round 6
// baseline (12.900 us; speedup 1.0000x reference)
//
#include <hip/hip_runtime.h>
#include <math.h>

#define N_IN   128
#define N_OUT  128
#define BATCH  512
#define NB     11
#define FJ     12
#define KD     (N_IN * FJ)         // 1536
#define LSTR   1544                // bf16 row stride; LSTR-1536 = 8

typedef __attribute__((ext_vector_type(8))) short bf16x8;
typedef __attribute__((ext_vector_type(4))) float f32x4;

static __device__ __forceinline__ unsigned short f2bf(float f) {
    union { float f; unsigned u; } v; v.f = f;
    unsigned r = v.u + 0x7FFF + ((v.u >> 16) & 1);   // RNE
    return (unsigned short)(r >> 16);
}

// Fused KAN: block = 16x16 output tile, 512 thr. LDS-built bf16 F/W, MFMA.
// W-build reads c_basis as lane-interleaved float4 (block slice is contiguous).
__global__ __launch_bounds__(512) void kan_fused2(
    const float* __restrict__ x, const float* __restrict__ grid,
    const float* __restrict__ c_basis, const float* __restrict__ c_res,
    const float* __restrict__ c_spl, float* __restrict__ out)
{
    __shared__ unsigned short Fl[16 * LSTR];   // 49.4 KB
    __shared__ unsigned short Wl[16 * LSTR];   // 49.4 KB
    __shared__ float Spl[16 * N_IN];           // 8 KB
    __shared__ float part[8][256];             // 8 KB
    const int t  = threadIdx.x;
    const int m0 = blockIdx.x * 16;            // batch rows
    const int n0 = blockIdx.y * 16;            // output cols

    // ---- issue all global loads early (independent -> deep ILP) ----
    const float4 sp4 = ((const float4*)(c_spl + n0 * N_IN))[t];   // 2048 = 512 f4
    const float4 rs4 = ((const float4*)(c_res + n0 * N_IN))[t];
    const float* CB  = c_basis + (size_t)n0 * N_IN * NB;          // contiguous 22528 f
    float4 cbv[11];
    #pragma unroll
    for (int m = 0; m < 11; ++m) cbv[m] = ((const float4*)CB)[m * 512 + t];

    ((float4*)Spl)[t] = sp4;

    // ---- c_res -> W[.][i*12+11] (4 b16 scatter) ----
    #pragma unroll
    for (int k = 0; k < 4; ++k) {
        const int e = 4 * t + k;               // local o*128+i
        Wl[(e >> 7) * LSTR + (e & 127) * FJ + 11] = f2bf(((const float*)&rs4)[k]);
    }

    // ---- F build: 2048 evals, 4/thread, coalesced x loads ----
    const float lo = grid[3];
    const float hr = 1.0f / (grid[4] - grid[3]);
    #pragma unroll
    for (int r = 0; r < 4; ++r) {
        const int p  = t + r * 512;
        const int bl = p >> 7;
        const int i  = p & 127;
        const float xv = x[(m0 + bl) * N_IN + i];
        const float s  = (xv - lo) * hr;       // in [0,8)
        int c = (int)s; c = c < 0 ? 0 : (c > 7 ? 7 : c);
        const float u  = s - (float)c;
        const float um = 1.0f - u;
        const float u2 = u * u, u3 = u2 * u;
        const float B0 = um * um * um * (1.0f / 6.0f);
        const float B1 = (3.0f * u3 - 6.0f * u2 + 4.0f) * (1.0f / 6.0f);
        const float B2 = (-3.0f * u3 + 3.0f * u2 + 3.0f * u + 1.0f) * (1.0f / 6.0f);
        const float B3 = u3 * (1.0f / 6.0f);
        float fv[12];
        #pragma unroll
        for (int j = 0; j < NB; ++j) {
            const int d = j - c;
            fv[j] = (d == 0) ? B0 : (d == 1) ? B1 : (d == 2) ? B2 : (d == 3) ? B3 : 0.0f;
        }
        fv[11] = xv / (1.0f + __expf(-xv));    // silu
        unsigned int* dst = (unsigned int*)&Fl[bl * LSTR + i * FJ];
        #pragma unroll
        for (int j = 0; j < 6; ++j)
            dst[j] = (unsigned)f2bf(fv[2*j]) | ((unsigned)f2bf(fv[2*j+1]) << 16);
    }

    __syncthreads();   // Spl visible

    // ---- W build: 44 elements/thread from the coalesced float4s ----
    #pragma unroll
    for (int m = 0; m < 11; ++m) {
        const int f0 = (m * 512 + t) * 4;
        #pragma unroll
        for (int k = 0; k < 4; ++k) {
            const int f = f0 + k;              // flat idx into 2048x11
            const int e = f / 11;              // magic div
            const int j = f - e * 11;
            const float w = ((const float*)&cbv[m])[k] * Spl[e];
            // addr = (e>>7)*LSTR + (e&127)*12 + j  ==  f + e + (e>>7)*8
            Wl[f + e + ((e >> 7) << 3)] = f2bf(w);
        }
    }

    __syncthreads();   // F/W ready

    // ---- MFMA: 8 waves split K=1536 into 8x192 -> 6 MFMA each ----
    const int wv   = t >> 6;
    const int lane = t & 63;
    const int row  = lane & 15;
    const int kq   = (lane >> 4) * 8;
    const int k0   = wv * (KD / 8);
    f32x4 acc = {0.f, 0.f, 0.f, 0.f};
    #pragma unroll
    for (int ks = 0; ks < 6; ++ks) {
        const int k = k0 + ks * 32 + kq;
        const bf16x8 a = *(const bf16x8*)&Fl[row * LSTR + k];
        const bf16x8 b = *(const bf16x8*)&Wl[row * LSTR + k];
        acc = __builtin_amdgcn_mfma_f32_16x16x32_bf16(a, b, acc, 0, 0, 0);
    }

    // C/D layout (m89): col = lane&15, row = (lane>>4)*4 + r
    #pragma unroll
    for (int r = 0; r < 4; ++r)
        part[wv][((lane >> 4) * 4 + r) * 16 + (lane & 15)] = acc[r];
    __syncthreads();

    if (t < 256) {
        float s = part[0][t] + part[1][t] + part[2][t] + part[3][t]
                + part[4][t] + part[5][t] + part[6][t] + part[7][t];
        out[(m0 + (t >> 4)) * N_OUT + n0 + (t & 15)] = s;
    }
}

extern "C" void kernel_launch(void* const* d_in, const int* in_sizes, int n_in,
                              void* d_out, int out_size, void* d_ws, size_t ws_size,
                              hipStream_t stream) {
    const float* x       = (const float*)d_in[0];
    const float* grid    = (const float*)d_in[1];
    const float* c_basis = (const float*)d_in[2];
    const float* c_res   = (const float*)d_in[3];
    const float* c_spl   = (const float*)d_in[4];
    float* out = (float*)d_out;

    dim3 g(BATCH / 16, N_OUT / 16);            // 32 x 8 = 256 blocks, 1/CU
    kan_fused2<<<g, 512, 0, stream>>>(x, grid, c_basis, c_res, c_spl, out);
}

// Round 8
// 12.604 us; speedup vs baseline: 1.0235x; 1.0235x over previous
//
#include <hip/hip_runtime.h>
#include <hip/hip_bf16.h>
#include <math.h>

#define N_IN   128
#define N_OUT  128
#define BATCH  512
#define NB     11
#define FJ     12
#define KD     (N_IN * FJ)         // 1536
#define LSTR   1544                // bf16 row stride; LSTR-1536 = 8

typedef __attribute__((ext_vector_type(8))) short bf16x8;
typedef __attribute__((ext_vector_type(4))) float f32x4;

// native bf16 RNE converts (compiler lowers these well; m240: don't hand-roll)
static __device__ __forceinline__ unsigned short bf1(float a) {
    __hip_bfloat16 h = __float2bfloat16(a);
    return *reinterpret_cast<unsigned short*>(&h);
}
static __device__ __forceinline__ unsigned pkbf(float a, float b) {
    return (unsigned)bf1(a) | ((unsigned)bf1(b) << 16);
}

// Fused KAN: block = 16x16 output tile, 512 thr (8 waves), 256 blocks = 1/CU.
// Phase 1: build F[16][1536] (basis+silu) and W[16][1536] (c_spl*c_basis ‖ c_res)
// in LDS as bf16.  Phase 2: 8-way K-split MFMA + cross-wave reduce.
__global__ __launch_bounds__(512) void kan_fused3(
    const float* __restrict__ x, const float* __restrict__ grid,
    const float* __restrict__ c_basis, const float* __restrict__ c_res,
    const float* __restrict__ c_spl, float* __restrict__ out)
{
    __shared__ unsigned short Fl[16 * LSTR];   // 49.4 KB
    __shared__ unsigned short Wl[16 * LSTR];   // 49.4 KB
    __shared__ float Spl[16 * N_IN];           // 8 KB
    __shared__ float part[8][256];             // 8 KB
    const int t  = threadIdx.x;
    const int m0 = blockIdx.x * 16;            // batch rows
    const int n0 = blockIdx.y * 16;            // output cols

    // ---- issue x loads FIRST (F-build consumes them first) ----
    float xr[4];
    #pragma unroll
    for (int r = 0; r < 4; ++r) {
        const int p = t + r * 512;
        xr[r] = x[(m0 + (p >> 7)) * N_IN + (p & 127)];
    }
    // ---- then the W-side operands (coalesced float4, consumed after barrier) ----
    const float4 sp4 = ((const float4*)(c_spl + n0 * N_IN))[t];
    const float4 rs4 = ((const float4*)(c_res + n0 * N_IN))[t];
    const float* CB  = c_basis + (size_t)n0 * N_IN * NB;   // contiguous block slice
    float4 cbv[11];
    #pragma unroll
    for (int m = 0; m < 11; ++m) cbv[m] = ((const float4*)CB)[m * 512 + t];

    ((float4*)Spl)[t] = sp4;

    // ---- c_res -> W[.][i*12+11] ----
    #pragma unroll
    for (int k = 0; k < 4; ++k) {
        const int e = 4 * t + k;               // local o*128+i
        Wl[(e >> 7) * LSTR + (e & 127) * FJ + 11] = bf1(((const float*)&rs4)[k]);
    }

    // ---- F build: 2048 evals, 4/thread ----
    const float lo = grid[3];
    const float hr = 1.0f / (grid[4] - grid[3]);
    #pragma unroll
    for (int r = 0; r < 4; ++r) {
        const int p  = t + r * 512;
        const int bl = p >> 7;
        const int i  = p & 127;
        const float xv = xr[r];
        const float s  = (xv - lo) * hr;       // in [0,8)
        int c = (int)s; c = c < 0 ? 0 : (c > 7 ? 7 : c);
        const float u  = s - (float)c;
        const float um = 1.0f - u;
        const float u2 = u * u, u3 = u2 * u;
        const float B0 = um * um * um * (1.0f / 6.0f);
        const float B1 = (3.0f * u3 - 6.0f * u2 + 4.0f) * (1.0f / 6.0f);
        const float B2 = (-3.0f * u3 + 3.0f * u2 + 3.0f * u + 1.0f) * (1.0f / 6.0f);
        const float B3 = u3 * (1.0f / 6.0f);
        float fv[12];
        #pragma unroll
        for (int j = 0; j < NB; ++j) {
            const int d = j - c;
            fv[j] = (d == 0) ? B0 : (d == 1) ? B1 : (d == 2) ? B2 : (d == 3) ? B3 : 0.0f;
        }
        fv[11] = xv / (1.0f + __expf(-xv));    // silu
        unsigned int* dst = (unsigned int*)&Fl[bl * LSTR + i * FJ];
        #pragma unroll
        for (int j = 0; j < 6; ++j)
            dst[j] = pkbf(fv[2 * j], fv[2 * j + 1]);
    }

    __syncthreads();   // Spl visible

    // ---- W build: 44 elements/thread from coalesced float4s ----
    #pragma unroll
    for (int m = 0; m < 11; ++m) {
        const int f0 = (m * 512 + t) * 4;
        #pragma unroll
        for (int k = 0; k < 4; ++k) {
            const int f = f0 + k;              // flat idx into 2048x11
            const int e = f / 11;              // magic div
            const float w = ((const float*)&cbv[m])[k] * Spl[e];
            // addr = (e>>7)*LSTR + (e&127)*12 + j  ==  f + e + (e>>7)*8
            Wl[f + e + ((e >> 7) << 3)] = bf1(w);
        }
    }

    __syncthreads();   // F/W ready

    // ---- MFMA: 8 waves split K=1536 into 8x192 -> 6 MFMA each ----
    const int wv   = t >> 6;
    const int lane = t & 63;
    const int row  = lane & 15;
    const int kq   = (lane >> 4) * 8;
    const int k0   = wv * (KD / 8);
    f32x4 acc = {0.f, 0.f, 0.f, 0.f};
    #pragma unroll
    for (int ks = 0; ks < 6; ++ks) {
        const int k = k0 + ks * 32 + kq;
        const bf16x8 a = *(const bf16x8*)&Fl[row * LSTR + k];
        const bf16x8 b = *(const bf16x8*)&Wl[row * LSTR + k];
        acc = __builtin_amdgcn_mfma_f32_16x16x32_bf16(a, b, acc, 0, 0, 0);
    }

    // C/D layout (m89): col = lane&15, row = (lane>>4)*4 + r
    #pragma unroll
    for (int r = 0; r < 4; ++r)
        part[wv][((lane >> 4) * 4 + r) * 16 + (lane & 15)] = acc[r];
    __syncthreads();

    if (t < 256) {
        float s = part[0][t] + part[1][t] + part[2][t] + part[3][t]
                + part[4][t] + part[5][t] + part[6][t] + part[7][t];
        out[(m0 + (t >> 4)) * N_OUT + n0 + (t & 15)] = s;
    }
}

extern "C" void kernel_launch(void* const* d_in, const int* in_sizes, int n_in,
                              void* d_out, int out_size, void* d_ws, size_t ws_size,
                              hipStream_t stream) {
    const float* x       = (const float*)d_in[0];
    const float* grid    = (const float*)d_in[1];
    const float* c_basis = (const float*)d_in[2];
    const float* c_res   = (const float*)d_in[3];
    const float* c_spl   = (const float*)d_in[4];
    float* out = (float*)d_out;

    dim3 g(BATCH / 16, N_OUT / 16);            // 32 x 8 = 256 blocks, 1/CU
    kan_fused3<<<g, 512, 0, stream>>>(x, grid, c_basis, c_res, c_spl, out);
}

// Round 9
// 12.594 us; speedup vs baseline: 1.0243x; 1.0008x over previous
//
#include <hip/hip_runtime.h>
#include <hip/hip_bf16.h>
#include <math.h>

#define N_IN   128
#define N_OUT  128
#define BATCH  512
#define NB     11
#define FJ     12
#define KD     (N_IN * FJ)         // 1536
#define LSTR   1544                // bf16 row stride; LSTR-1536 = 8

typedef __attribute__((ext_vector_type(8))) short bf16x8;
typedef __attribute__((ext_vector_type(4))) float f32x4;

// native bf16 RNE converts (compiler lowers these well; m240: don't hand-roll)
static __device__ __forceinline__ unsigned short bf1(float a) {
    __hip_bfloat16 h = __float2bfloat16(a);
    return *reinterpret_cast<unsigned short*>(&h);
}
static __device__ __forceinline__ unsigned pkbf(float a, float b) {
    return (unsigned)bf1(a) | ((unsigned)bf1(b) << 16);
}

// Fused KAN: block = 16x16 output tile, 512 thr (8 waves), 256 blocks = 1/CU.
// 1-D grid + XCD swizzle: n-group = bid&7 -> all 32 blocks sharing a c_basis
// slice land on ONE XCD (round-robin dispatch), so the 90 KB slice is fetched
// from HBM once per XCD instead of 32x.  [T1]
__global__ __launch_bounds__(512) void kan_fused4(
    const float* __restrict__ x, const float* __restrict__ grid,
    const float* __restrict__ c_basis, const float* __restrict__ c_res,
    const float* __restrict__ c_spl, float* __restrict__ out)
{
    __shared__ unsigned short Fl[16 * LSTR];   // 49.4 KB
    __shared__ unsigned short Wl[16 * LSTR];   // 49.4 KB
    __shared__ float Spl[16 * N_IN];           // 8 KB
    __shared__ float part[8][256];             // 8 KB
    const int t   = threadIdx.x;
    const int bid = blockIdx.x;
    const int m0  = (bid >> 3) * 16;           // batch rows   (32 groups)
    const int n0  = (bid & 7) * 16;            // output cols  (8 groups = 8 XCDs)

    // ---- issue x loads FIRST (F-build consumes them first) ----
    float xr[4];
    #pragma unroll
    for (int r = 0; r < 4; ++r) {
        const int p = t + r * 512;
        xr[r] = x[(m0 + (p >> 7)) * N_IN + (p & 127)];
    }
    // ---- then the W-side operands (coalesced float4, consumed after barrier) ----
    const float4 sp4 = ((const float4*)(c_spl + n0 * N_IN))[t];
    const float4 rs4 = ((const float4*)(c_res + n0 * N_IN))[t];
    const float* CB  = c_basis + (size_t)n0 * N_IN * NB;   // contiguous block slice
    float4 cbv[11];
    #pragma unroll
    for (int m = 0; m < 11; ++m) cbv[m] = ((const float4*)CB)[m * 512 + t];

    ((float4*)Spl)[t] = sp4;

    // ---- c_res -> W[.][i*12+11] ----
    #pragma unroll
    for (int k = 0; k < 4; ++k) {
        const int e = 4 * t + k;               // local o*128+i
        Wl[(e >> 7) * LSTR + (e & 127) * FJ + 11] = bf1(((const float*)&rs4)[k]);
    }

    // ---- F build: 2048 evals, 4/thread ----
    const float lo = grid[3];
    const float hr = 1.0f / (grid[4] - grid[3]);
    #pragma unroll
    for (int r = 0; r < 4; ++r) {
        const int p  = t + r * 512;
        const int bl = p >> 7;
        const int i  = p & 127;
        const float xv = xr[r];
        const float s  = (xv - lo) * hr;       // in [0,8)
        int c = (int)s; c = c < 0 ? 0 : (c > 7 ? 7 : c);
        const float u  = s - (float)c;
        const float um = 1.0f - u;
        const float u2 = u * u, u3 = u2 * u;
        const float B0 = um * um * um * (1.0f / 6.0f);
        const float B1 = (3.0f * u3 - 6.0f * u2 + 4.0f) * (1.0f / 6.0f);
        const float B2 = (-3.0f * u3 + 3.0f * u2 + 3.0f * u + 1.0f) * (1.0f / 6.0f);
        const float B3 = u3 * (1.0f / 6.0f);
        float fv[12];
        #pragma unroll
        for (int j = 0; j < NB; ++j) {
            const int d = j - c;
            fv[j] = (d == 0) ? B0 : (d == 1) ? B1 : (d == 2) ? B2 : (d == 3) ? B3 : 0.0f;
        }
        fv[11] = xv / (1.0f + __expf(-xv));    // silu
        unsigned int* dst = (unsigned int*)&Fl[bl * LSTR + i * FJ];
        #pragma unroll
        for (int j = 0; j < 6; ++j)
            dst[j] = pkbf(fv[2 * j], fv[2 * j + 1]);
    }

    __syncthreads();   // Spl visible

    // ---- W build: 44 elements/thread from coalesced float4s ----
    #pragma unroll
    for (int m = 0; m < 11; ++m) {
        const int f0 = (m * 512 + t) * 4;
        #pragma unroll
        for (int k = 0; k < 4; ++k) {
            const int f = f0 + k;              // flat idx into 2048x11
            const int e = f / 11;              // magic div
            const float w = ((const float*)&cbv[m])[k] * Spl[e];
            // addr = (e>>7)*LSTR + (e&127)*12 + j  ==  f + e + (e>>7)*8
            Wl[f + e + ((e >> 7) << 3)] = bf1(w);
        }
    }

    __syncthreads();   // F/W ready

    // ---- MFMA: 8 waves split K=1536 into 8x192 -> 6 MFMA each ----
    const int wv   = t >> 6;
    const int lane = t & 63;
    const int row  = lane & 15;
    const int kq   = (lane >> 4) * 8;
    const int k0   = wv * (KD / 8);
    f32x4 acc = {0.f, 0.f, 0.f, 0.f};
    #pragma unroll
    for (int ks = 0; ks < 6; ++ks) {
        const int k = k0 + ks * 32 + kq;
        const bf16x8 a = *(const bf16x8*)&Fl[row * LSTR + k];
        const bf16x8 b = *(const bf16x8*)&Wl[row * LSTR + k];
        acc = __builtin_amdgcn_mfma_f32_16x16x32_bf16(a, b, acc, 0, 0, 0);
    }

    // C/D layout (m89): col = lane&15, row = (lane>>4)*4 + r
    #pragma unroll
    for (int r = 0; r < 4; ++r)
        part[wv][((lane >> 4) * 4 + r) * 16 + (lane & 15)] = acc[r];
    __syncthreads();

    if (t < 256) {
        float s = part[0][t] + part[1][t] + part[2][t] + part[3][t]
                + part[4][t] + part[5][t] + part[6][t] + part[7][t];
        out[(m0 + (t >> 4)) * N_OUT + n0 + (t & 15)] = s;
    }
}

extern "C" void kernel_launch(void* const* d_in, const int* in_sizes, int n_in,
                              void* d_out, int out_size, void* d_ws, size_t ws_size,
                              hipStream_t stream) {
    const float* x       = (const float*)d_in[0];
    const float* grid    = (const float*)d_in[1];
    const float* c_basis = (const float*)d_in[2];
    const float* c_res   = (const float*)d_in[3];
    const float* c_spl   = (const float*)d_in[4];
    float* out = (float*)d_out;

    kan_fused4<<<256, 512, 0, stream>>>(x, grid, c_basis, c_res, c_spl, out);
}

// Round 10
// 11.416 us; speedup vs baseline: 1.1300x; 1.1032x over previous
//
#include <hip/hip_runtime.h>
#include <hip/hip_bf16.h>
#include <math.h>

#define N_IN   128
#define N_OUT  128
#define BATCH  512
#define NB     11
#define FJ     12
#define KD     (N_IN * FJ)         // 1536
#define LSTR   1544                // bf16 row stride; 3088 B ≡ 4 words mod 32 banks

typedef __attribute__((ext_vector_type(8))) short bf16x8;
typedef __attribute__((ext_vector_type(4))) float f32x4;

static __device__ __forceinline__ unsigned short bf1(float a) {
    __hip_bfloat16 h = __float2bfloat16(a);
    return *reinterpret_cast<unsigned short*>(&h);
}
static __device__ __forceinline__ unsigned pkbf(float a, float b) {
    return (unsigned)bf1(a) | ((unsigned)bf1(b) << 16);
}

// Fused KAN, minimal-critical-path version:
//  - thread t owns W edges e = t + 512r  -> spl/res/c_basis lane-local in regs
//    (no Spl LDS staging, no magic div, no pre-MFMA barrier #1)
//  - all global loads issued upfront; F and W built independently; ONE barrier
//  - LDS writes as uint2 (ds_write_b64), rows 24 B -> 4-way bank alias max
__global__ __launch_bounds__(512) void kan_fused5(
    const float* __restrict__ x, const float* __restrict__ grid,
    const float* __restrict__ c_basis, const float* __restrict__ c_res,
    const float* __restrict__ c_spl, float* __restrict__ out)
{
    __shared__ unsigned short Fl[16 * LSTR];   // 49.4 KB
    __shared__ unsigned short Wl[16 * LSTR];   // 49.4 KB
    __shared__ float part[8][256];             // 8 KB
    const int t   = threadIdx.x;
    const int bid = blockIdx.x;
    const int m0  = (bid >> 3) * 16;           // batch rows   (32 groups)
    const int n0  = (bid & 7) * 16;            // output cols  (8 XCD-pinned groups)

    // ---- issue ALL global loads upfront (independent -> deep ILP) ----
    float xr[4];
    #pragma unroll
    for (int r = 0; r < 4; ++r) {
        const int p = t + r * 512;
        xr[r] = x[(m0 + (p >> 7)) * N_IN + (p & 127)];
    }
    float cb[4][NB], spl[4], res[4];
    #pragma unroll
    for (int r = 0; r < 4; ++r) {
        const size_t e = (size_t)n0 * N_IN + t + 512 * r;
        const float* cp = c_basis + e * NB;
        #pragma unroll
        for (int j = 0; j < NB; ++j) cb[r][j] = cp[j];
        spl[r] = c_spl[e];
        res[r] = c_res[e];
    }

    // ---- F build: 4 evals/thread, 12 bf16 packed -> 3 ds_write_b64 ----
    const float lo = grid[3];
    const float hr = 1.0f / (grid[4] - grid[3]);
    #pragma unroll
    for (int r = 0; r < 4; ++r) {
        const int p  = t + r * 512;
        const int bl = p >> 7;
        const int i  = p & 127;
        const float xv = xr[r];
        const float s  = (xv - lo) * hr;       // in [0,8)
        int c = (int)s; c = c < 0 ? 0 : (c > 7 ? 7 : c);
        const float u  = s - (float)c;
        const float um = 1.0f - u;
        const float u2 = u * u, u3 = u2 * u;
        const float B0 = um * um * um * (1.0f / 6.0f);
        const float B1 = (3.0f * u3 - 6.0f * u2 + 4.0f) * (1.0f / 6.0f);
        const float B2 = (-3.0f * u3 + 3.0f * u2 + 3.0f * u + 1.0f) * (1.0f / 6.0f);
        const float B3 = u3 * (1.0f / 6.0f);
        float fv[12];
        #pragma unroll
        for (int j = 0; j < NB; ++j) {
            const int d = j - c;
            fv[j] = (d == 0) ? B0 : (d == 1) ? B1 : (d == 2) ? B2 : (d == 3) ? B3 : 0.0f;
        }
        fv[11] = xv / (1.0f + __expf(-xv));    // silu
        uint2* dst = (uint2*)&Fl[bl * LSTR + i * FJ];   // 8B-aligned (24i, 3088bl)
        dst[0] = make_uint2(pkbf(fv[0], fv[1]), pkbf(fv[2],  fv[3]));
        dst[1] = make_uint2(pkbf(fv[4], fv[5]), pkbf(fv[6],  fv[7]));
        dst[2] = make_uint2(pkbf(fv[8], fv[9]), pkbf(fv[10], fv[11]));
    }

    // ---- W build: lane-local rows, no barrier needed before this ----
    #pragma unroll
    for (int r = 0; r < 4; ++r) {
        const int ol = (t >> 7) + 4 * r;       // (t + 512r) >> 7
        const int i  = t & 127;
        float wv[12];
        #pragma unroll
        for (int j = 0; j < NB; ++j) wv[j] = spl[r] * cb[r][j];
        wv[11] = res[r];
        uint2* dst = (uint2*)&Wl[ol * LSTR + i * FJ];
        dst[0] = make_uint2(pkbf(wv[0], wv[1]), pkbf(wv[2],  wv[3]));
        dst[1] = make_uint2(pkbf(wv[4], wv[5]), pkbf(wv[6],  wv[7]));
        dst[2] = make_uint2(pkbf(wv[8], wv[9]), pkbf(wv[10], wv[11]));
    }

    __syncthreads();   // single pre-MFMA barrier

    // ---- MFMA: 8 waves split K=1536 into 8x192 -> 6 MFMA each ----
    const int wv_  = t >> 6;
    const int lane = t & 63;
    const int row  = lane & 15;
    const int kq   = (lane >> 4) * 8;
    const int k0   = wv_ * (KD / 8);
    f32x4 acc = {0.f, 0.f, 0.f, 0.f};
    #pragma unroll
    for (int ks = 0; ks < 6; ++ks) {
        const int k = k0 + ks * 32 + kq;
        const bf16x8 a = *(const bf16x8*)&Fl[row * LSTR + k];
        const bf16x8 b = *(const bf16x8*)&Wl[row * LSTR + k];
        acc = __builtin_amdgcn_mfma_f32_16x16x32_bf16(a, b, acc, 0, 0, 0);
    }

    // C/D layout (m89): col = lane&15, row = (lane>>4)*4 + r
    #pragma unroll
    for (int r = 0; r < 4; ++r)
        part[wv_][((lane >> 4) * 4 + r) * 16 + (lane & 15)] = acc[r];
    __syncthreads();

    if (t < 256) {
        float s = part[0][t] + part[1][t] + part[2][t] + part[3][t]
                + part[4][t] + part[5][t] + part[6][t] + part[7][t];
        out[(m0 + (t >> 4)) * N_OUT + n0 + (t & 15)] = s;
    }
}

extern "C" void kernel_launch(void* const* d_in, const int* in_sizes, int n_in,
                              void* d_out, int out_size, void* d_ws, size_t ws_size,
                              hipStream_t stream) {
    const float* x       = (const float*)d_in[0];
    const float* grid    = (const float*)d_in[1];
    const float* c_basis = (const float*)d_in[2];
    const float* c_res   = (const float*)d_in[3];
    const float* c_spl   = (const float*)d_in[4];
    float* out = (float*)d_out;

    kan_fused5<<<256, 512, 0, stream>>>(x, grid, c_basis, c_res, c_spl, out);
}